// Round 1
// 374.654 us; speedup vs baseline: 1.0470x; 1.0470x over previous
//
#include <hip/hip_runtime.h>
#include <math.h>

#define NN 8192
#define IN_DIM 64
#define GAT_EPS 1e-10f
#define ECAP 256   // per-row edge capacity; Binom(8192,0.005): mean 41, max ~80. 256 = safe.

typedef float fvec4 __attribute__((ext_vector_type(4)));

__device__ __forceinline__ unsigned nz4(fvec4 v) {
    return (unsigned)(v.x != 0.f) | ((unsigned)(v.y != 0.f) << 1) |
           ((unsigned)(v.z != 0.f) << 2) | ((unsigned)(v.w != 0.f) << 3);
}

// ---------------------------------------------------------------------------
// Kernel 1: per-node destination score factors only.
//   pdv[m] = { exp(feat[m].Wa0_dst), exp(feat[m].Wa1_dst) }
// Row factor exp(s_src+b) cancels in the softmax (rank-1 scores).
// The feature transform (old ftI) is gone entirely: since rows of attn sum
// to 1, W_lin(Σ a x) + b == Σ a (W_lin x + b) — applied post-aggregation.
// ---------------------------------------------------------------------------
__global__ void pdv_kernel(const float* __restrict__ features,
                           const float* __restrict__ W_attn,
                           float2* __restrict__ pdv) {
    int n = blockIdx.x * blockDim.x + threadIdx.x;  // 32 blocks x 256 = 8192
    const float4* f4   = (const float4*)(features + (size_t)n * IN_DIM);
    const float4* wa0d = (const float4*)(W_attn + IN_DIM);
    const float4* wa1d = (const float4*)(W_attn + 3 * IN_DIM);
    float s0 = 0.f, s1 = 0.f;
#pragma unroll
    for (int d = 0; d < IN_DIM / 4; ++d) {
        float4 f = f4[d];
        float4 b = wa0d[d];
        float4 e = wa1d[d];
        s0 += f.x * b.x + f.y * b.y + f.z * b.z + f.w * b.w;
        s1 += f.x * e.x + f.y * e.y + f.z * e.z + f.w * e.w;
    }
    pdv[n] = make_float2(__expf(s0), __expf(s1));
}

// ---------------------------------------------------------------------------
// Kernel 2: one wave per row (session-best structure), phase-A adj stream
// pipelined 3 rounds (12 loads) ahead, nontemporal so the stream does not
// thrash L2/L3 (features/pdv/W_lin stay hot). Phase B drains the LDS edge
// list 8-at-a-time gathering RAW features (4 B/lane/edge, shared by both
// heads). Epilogue: normalize, stage agg in LDS, 2x 64x64 matvec vs L2-hot
// W_lin, bias, ELU.
// ---------------------------------------------------------------------------
__global__ void __launch_bounds__(256) gat_agg_kernel(
        const float* __restrict__ adj,
        const float* __restrict__ features,
        const float2* __restrict__ pdv,
        const float* __restrict__ W_lin,
        const float* __restrict__ b_lin,
        float* __restrict__ out) {
    __shared__ int edges[4][ECAP];
    __shared__ int ecnt[4];
    __shared__ float aggbuf[4][2][64];
    int widx = threadIdx.x >> 6;
    int lane = threadIdx.x & 63;
    int n = blockIdx.x * 4 + widx;
    int* ebuf = edges[widx];

    if (lane == 0) ecnt[widx] = 0;

    const fvec4* arow = (const fvec4*)(adj + (size_t)n * NN) + lane;

    // software pipeline: 3 rounds (12 loads, 12 KB/wave) in flight
    fvec4 q[3][4];
#pragma unroll
    for (int r = 0; r < 3; ++r) {
        const fvec4* p = arow + r * 256;
        q[r][0] = __builtin_nontemporal_load(p);
        q[r][1] = __builtin_nontemporal_load(p + 64);
        q[r][2] = __builtin_nontemporal_load(p + 128);
        q[r][3] = __builtin_nontemporal_load(p + 192);
    }

#pragma unroll
    for (int it = 0; it < 8; ++it) {   // fully unrolled; 1024 cols per round
        int slot = it % 3;
        fvec4 a0 = q[slot][0], a1 = q[slot][1], a2 = q[slot][2], a3 = q[slot][3];
        if (it < 5) {
            const fvec4* p = arow + (it + 3) * 256;
            q[slot][0] = __builtin_nontemporal_load(p);
            q[slot][1] = __builtin_nontemporal_load(p + 64);
            q[slot][2] = __builtin_nontemporal_load(p + 128);
            q[slot][3] = __builtin_nontemporal_load(p + 192);
        }
        unsigned mb = nz4(a0) | (nz4(a1) << 4) | (nz4(a2) << 8) | (nz4(a3) << 12);
        if (mb) {
            int c = __popc(mb);
            int pos = atomicAdd(&ecnt[widx], c);
            int megabase = it * 1024 + lane * 4;
            while (mb) {
                int b = __ffs(mb) - 1;
                mb &= mb - 1;
                ebuf[pos++] = megabase + ((b >> 2) << 8) + (b & 3);
            }
        }
    }

    // self-loop (+I): weight pdv[n], raw feature value
    float2 ps = pdv[n];
    float fs = features[(size_t)n * 64 + lane];
    float acc0 = ps.x * fs, acc1 = ps.y * fs;
    float den0 = ps.x, den1 = ps.y;

    __syncthreads();

    int count = ecnt[widx];
    int e = 0;
    for (; e + 8 <= count; e += 8) {
        int4 ma  = *(const int4*)&ebuf[e];
        int4 mbq = *(const int4*)&ebuf[e + 4];
        float2 p0 = pdv[ma.x],  p1 = pdv[ma.y],  p2 = pdv[ma.z],  p3 = pdv[ma.w];
        float2 p4 = pdv[mbq.x], p5 = pdv[mbq.y], p6 = pdv[mbq.z], p7 = pdv[mbq.w];
        float f0 = features[(size_t)ma.x * 64 + lane];
        float f1 = features[(size_t)ma.y * 64 + lane];
        float f2 = features[(size_t)ma.z * 64 + lane];
        float f3 = features[(size_t)ma.w * 64 + lane];
        float f4v = features[(size_t)mbq.x * 64 + lane];
        float f5 = features[(size_t)mbq.y * 64 + lane];
        float f6 = features[(size_t)mbq.z * 64 + lane];
        float f7 = features[(size_t)mbq.w * 64 + lane];
        acc0 += p0.x * f0 + p1.x * f1 + p2.x * f2 + p3.x * f3
              + p4.x * f4v + p5.x * f5 + p6.x * f6 + p7.x * f7;
        acc1 += p0.y * f0 + p1.y * f1 + p2.y * f2 + p3.y * f3
              + p4.y * f4v + p5.y * f5 + p6.y * f6 + p7.y * f7;
        den0 += p0.x + p1.x + p2.x + p3.x + p4.x + p5.x + p6.x + p7.x;
        den1 += p0.y + p1.y + p2.y + p3.y + p4.y + p5.y + p6.y + p7.y;
    }
    for (; e < count; ++e) {
        int m = ebuf[e];
        float2 p = pdv[m];
        float f = features[(size_t)m * 64 + lane];
        acc0 += p.x * f;
        acc1 += p.y * f;
        den0 += p.x;
        den1 += p.y;
    }

    // normalize and stage aggregated (pre-transform) features in LDS
    aggbuf[widx][0][lane] = acc0 / (den0 + GAT_EPS);
    aggbuf[widx][1][lane] = acc1 / (den1 + GAT_EPS);
    __syncthreads();

    // epilogue: out[n, h*64+j] = W_lin[h*64+j,:] . agg_h + b_lin[h*64+j], ELU
    const float4* w0 = (const float4*)(W_lin + (size_t)lane * IN_DIM);
    const float4* w1 = (const float4*)(W_lin + (size_t)(64 + lane) * IN_DIM);
    const float4* a0p = (const float4*)aggbuf[widx][0];
    const float4* a1p = (const float4*)aggbuf[widx][1];
    float o0 = 0.f, o1 = 0.f;
#pragma unroll
    for (int d = 0; d < IN_DIM / 4; ++d) {
        float4 u = w0[d];
        float4 x = a0p[d];     // LDS broadcast read (same addr all lanes)
        float4 v = w1[d];
        float4 y = a1p[d];
        o0 += u.x * x.x + u.y * x.y + u.z * x.z + u.w * x.w;
        o1 += v.x * y.x + v.y * y.y + v.z * y.z + v.w * y.w;
    }
    o0 += b_lin[lane];
    o1 += b_lin[64 + lane];
    o0 = o0 > 0.f ? o0 : expm1f(o0);
    o1 = o1 > 0.f ? o1 : expm1f(o1);
    out[(size_t)n * 128 + lane]      = o0;
    out[(size_t)n * 128 + 64 + lane] = o1;
}

extern "C" void kernel_launch(void* const* d_in, const int* in_sizes, int n_in,
                              void* d_out, int out_size, void* d_ws, size_t ws_size,
                              hipStream_t stream) {
    const float* adj      = (const float*)d_in[0];  // [N, N] binary
    const float* features = (const float*)d_in[1];  // [N, 64]
    const float* W_attn   = (const float*)d_in[2];  // [2, 128]
    // d_in[3] = b_attn: cancels in softmax normalization, unused
    const float* W_lin    = (const float*)d_in[4];  // [128, 64]
    const float* b_lin    = (const float*)d_in[5];  // [128]
    float* out = (float*)d_out;                     // [N, 128]

    float2* pdv = (float2*)d_ws;                    // 64 KB

    pdv_kernel<<<32, 256, 0, stream>>>(features, W_attn, pdv);
    gat_agg_kernel<<<NN / 4, 256, 0, stream>>>(adj, features, pdv, W_lin, b_lin, out);
}